// Round 1
// baseline (134.457 us; speedup 1.0000x reference)
//
#include <hip/hip_runtime.h>
#include <stdint.h>

typedef __attribute__((ext_vector_type(8))) short short8;
typedef __attribute__((ext_vector_type(4))) float floatx4;

#define MFMA(a, b, c) __builtin_amdgcn_mfma_f32_16x16x32_bf16(a, b, c, 0, 0, 0)

union Frag { uint32_t u[4]; short8 s; };

// split fp32 x into hi=bf16(trunc), lo=bf16(trunc of exact residual); pack two
// values' bf16 halves into one dword (a -> low16, b -> high16).
__device__ __forceinline__ void packsplit(float a, float b, uint32_t& hi, uint32_t& lo) {
    uint32_t ua = __float_as_uint(a), ub = __float_as_uint(b);
    uint32_t ha = ua & 0xFFFF0000u, hb = ub & 0xFFFF0000u;
    float ra = a - __uint_as_float(ha);   // exact in fp32
    float rb = b - __uint_as_float(hb);
    hi = (ha >> 16) | hb;
    lo = (__float_as_uint(ra) >> 16) | (__float_as_uint(rb) & 0xFFFF0000u);
}

__device__ __forceinline__ float fexp2(float x) {
#if __has_builtin(__builtin_amdgcn_exp2f)
    return __builtin_amdgcn_exp2f(x);     // v_exp_f32 = 2^x
#else
    return exp2f(x);
#endif
}

// LDS dword map (sm):
//  QK phase: K dbuf p in {0,1}: KHI=p*4608, KLO=p*4608+2304   (64 m-rows x 36 dw)
//  PV phase: Vt dbuf p:        VTHI=p*4608, VTLO=p*4608+2304  (64 d-rows x 36 dw, rotated cols)
//            P (single, wave-private rows): PHI=9216, PLO=11520 (64 t-rows x 36 dw)
#define PHIo 9216
#define PLOo 11520

__global__ __launch_bounds__(256, 2)
void msmha_mfma(const float* __restrict__ qg, const float* __restrict__ kg,
                const float* __restrict__ vg, const float* __restrict__ Dg,
                const float* __restrict__ m1w, const float* __restrict__ m1b,
                const float* __restrict__ m2w, const float* __restrict__ m2b,
                float* __restrict__ outg) {
    __shared__ __align__(16) uint32_t sm[13824];   // 54 KiB
    __shared__ __align__(16) float4 wlds[16];

    const int tid  = threadIdx.x;
    const int w    = tid >> 6;        // wave id: 16 t-rows each
    const int lane = tid & 63;
    const int col  = lane & 15;
    const int quad = lane >> 4;

    const int bid = blockIdx.x;
    const int wgT = bid & 7;          // 8 T-tiles of 64
    const int bh  = bid >> 3;
    const int h   = bh & 15;
    const int b   = bh >> 4;
    const int t0g = wgT * 64;

    const size_t base = (size_t)bh * 512 * 64;
    const float LOG2E = 1.4426950408889634f;

    // Channel weights, pre-scaled:  h_c = wv.x*dot_raw + wv.y*D + wv.z  (all xLOG2E,
    // dot scaling 1/8 folded into wv.x), wv.w = w2/2 for the |h| term.
    if (tid < 16) {
        const float w1d = m1w[h * 32 + tid];
        const float w1s = m1w[h * 32 + 16 + tid];
        const float b1  = m1b[h * 16 + tid];
        const float w2  = m2w[h * 16 + tid];
        wlds[tid] = make_float4(w1d * (0.125f * LOG2E), w1s * LOG2E, b1 * LOG2E, 0.5f * w2);
    }

    // Linear half of the relu split: sum_c w2*relu(h) = sum_c (w2/2)h + (w2/2)|h|.
    // The first sum is affine in (dot, D): Ac*dot_raw + Bc*D + Cc  (log2e-scaled).
    float sA = 0.f, sB = 0.f, sC = 0.f;
#pragma unroll 1
    for (int c = 0; c < 16; ++c) {
        const float w2 = m2w[h * 16 + c];
        sA = fmaf(w2, m1w[h * 32 + c], sA);
        sB = fmaf(w2, m1w[h * 32 + 16 + c], sB);
        sC = fmaf(w2, m1b[h * 16 + c], sC);
    }
    const float Ac = sA * (0.0625f * LOG2E);          // (1/2)(1/8) fold
    const float Bc = sB * (0.5f * LOG2E);
    const float Cc = fmaf(0.5f, sC, m2b[h]) * LOG2E;  // L*(b2 + 0.5*sum w2*b1)

    // Q fragments (B-operand: lane col = t-row, k = quad*8+j), split bf16
    Frag qh[2], ql[2];
    {
        const float* qrow = qg + base + (size_t)(t0g + w * 16 + col) * 64;
#pragma unroll
        for (int ks = 0; ks < 2; ++ks) {
            const float4 f0 = *(const float4*)(qrow + ks * 32 + quad * 8);
            const float4 f1 = *(const float4*)(qrow + ks * 32 + quad * 8 + 4);
            packsplit(f0.x, f0.y, qh[ks].u[0], ql[ks].u[0]);
            packsplit(f0.z, f0.w, qh[ks].u[1], ql[ks].u[1]);
            packsplit(f1.x, f1.y, qh[ks].u[2], ql[ks].u[2]);
            packsplit(f1.z, f1.w, qh[ks].u[3], ql[ks].u[3]);
        }
    }

    floatx4 accA[32];   // scores: lane holds t=col, m = mc*64 + mt*16 + quad*4 + r
    const float* Dbase = Dg + ((size_t)b * 512 + t0g + w * 16 + col) * 512 + quad * 4;

    // ---- K staging helpers (chunk = 64 m-rows, double-buffered) ----
    const int ml0 = tid >> 4;
    const int k4  = tid & 15;
    float4 kreg[4];
    auto kload = [&](int mc) {
#pragma unroll
        for (int it = 0; it < 4; ++it)
            kreg[it] = *(const float4*)(kg + base + (size_t)(mc * 64 + ml0 + it * 16) * 64 + k4 * 4);
    };
    auto kwrite = [&](int p) {
        uint32_t* KH = sm + p * 4608;
        uint32_t* KL = KH + 2304;
#pragma unroll
        for (int it = 0; it < 4; ++it) {
            uint32_t h0, l0, h1, l1;
            packsplit(kreg[it].x, kreg[it].y, h0, l0);
            packsplit(kreg[it].z, kreg[it].w, h1, l1);
            const int ml = ml0 + it * 16;
            *(uint2*)(KH + ml * 36 + 2 * k4) = make_uint2(h0, h1);
            *(uint2*)(KL + ml * 36 + 2 * k4) = make_uint2(l0, l1);
        }
    };

    kload(0);
    kwrite(0);
    __syncthreads();

    // ================= QK^T + fused MLP, 8 chunks of 64 m =================
#pragma unroll
    for (int mc = 0; mc < 8; ++mc) {
        const int p = mc & 1;
        if (mc < 7) kload(mc + 1);    // prefetch next chunk (in flight over compute)

        float4 dv[4];
#pragma unroll
        for (int mt = 0; mt < 4; ++mt)
            dv[mt] = *(const float4*)(Dbase + mc * 64 + mt * 16);

        const uint32_t* KH = sm + p * 4608;
        const uint32_t* KL = KH + 2304;
        floatx4 sc[4];
#pragma unroll
        for (int mt = 0; mt < 4; ++mt) {
            floatx4 acc = {0.f, 0.f, 0.f, 0.f};
#pragma unroll
            for (int ks = 0; ks < 2; ++ks) {
                const int ro = (mt * 16 + col) * 36 + 16 * ks + 4 * quad;
                Frag ah, al;
                ah.s = *(const short8*)(KH + ro);
                al.s = *(const short8*)(KL + ro);
                acc = MFMA(ah.s, qh[ks].s, acc);
                acc = MFMA(ah.s, ql[ks].s, acc);
                acc = MFMA(al.s, qh[ks].s, acc);
            }
            sc[mt] = acc;   // raw dot (unscaled)
        }

        float dvf[16];
#pragma unroll
        for (int mt = 0; mt < 4; ++mt) {
            dvf[mt * 4 + 0] = dv[mt].x; dvf[mt * 4 + 1] = dv[mt].y;
            dvf[mt * 4 + 2] = dv[mt].z; dvf[mt * 4 + 3] = dv[mt].w;
        }
        // mix = Cc + Bc*D + Ac*dot + sum_c (w2/2)|h_c|;  |..| is free input modifier
        float mix[16];
#pragma unroll
        for (int e = 0; e < 16; ++e) mix[e] = fmaf(dvf[e], Bc, Cc);
#pragma unroll 4
        for (int c = 0; c < 16; ++c) {
            const float4 wv = wlds[c];
#pragma unroll
            for (int mt = 0; mt < 4; ++mt)
#pragma unroll
                for (int r = 0; r < 4; ++r) {
                    const float hh = fmaf(sc[mt][r], wv.x, fmaf(dvf[mt * 4 + r], wv.y, wv.z));
                    mix[mt * 4 + r] = fmaf(fabsf(hh), wv.w, mix[mt * 4 + r]);
                }
        }
#pragma unroll
        for (int mt = 0; mt < 4; ++mt)
#pragma unroll
            for (int r = 0; r < 4; ++r)
                accA[mc * 4 + mt][r] = fmaf(sc[mt][r], Ac, mix[mt * 4 + r]);

        if (mc < 7) kwrite(p ^ 1);    // consume prefetch BEFORE barrier (vmcnt drained)
        __syncthreads();
    }

    // ---- V staging helpers (conflict-free: 4m x 4d block per thread, rotated cols) ----
    const int dgrp = tid & 15, m4 = tid >> 4;
    const int rotV = 8 * (dgrp & 3);
    float4 vreg[4];
    auto vload = [&](int mc) {
#pragma unroll
        for (int i = 0; i < 4; ++i)
            vreg[i] = *(const float4*)(vg + base + (size_t)(mc * 64 + 4 * m4 + i) * 64 + dgrp * 4);
    };
    auto vwrite = [&](int p) {
        uint32_t* VH = sm + p * 4608;
        uint32_t* VL = VH + 2304;
        const float a0[4] = {vreg[0].x, vreg[0].y, vreg[0].z, vreg[0].w};
        const float a1[4] = {vreg[1].x, vreg[1].y, vreg[1].z, vreg[1].w};
        const float a2[4] = {vreg[2].x, vreg[2].y, vreg[2].z, vreg[2].w};
        const float a3[4] = {vreg[3].x, vreg[3].y, vreg[3].z, vreg[3].w};
        const int cp = (2 * m4 + rotV) & 31;
#pragma unroll
        for (int jj = 0; jj < 4; ++jj) {
            uint32_t h0, l0, h1, l1;
            packsplit(a0[jj], a1[jj], h0, l0);   // m-pair (4m4, 4m4+1)
            packsplit(a2[jj], a3[jj], h1, l1);   // m-pair (4m4+2, 4m4+3)
            const int d = 4 * dgrp + jj;
            *(uint2*)(VH + d * 36 + cp) = make_uint2(h0, h1);
            *(uint2*)(VL + d * 36 + cp) = make_uint2(l0, l1);
        }
    };

    vload(0);   // V chunk-0 latency hides under the softmax below

    // ================= softmax over m (log2-domain scores) =================
    float mx = -3.4e38f;
#pragma unroll
    for (int i = 0; i < 32; ++i)
#pragma unroll
        for (int r = 0; r < 4; ++r) mx = fmaxf(mx, accA[i][r]);
    mx = fmaxf(mx, __shfl_xor(mx, 16, 64));
    mx = fmaxf(mx, __shfl_xor(mx, 32, 64));
    float sum = 0.f;
#pragma unroll
    for (int i = 0; i < 32; ++i)
#pragma unroll
        for (int r = 0; r < 4; ++r) {
            const float e = fexp2(accA[i][r] - mx);
            accA[i][r] = e;               // unnormalized; 1/sum folded into epilogue
            sum += e;
        }
    sum += __shfl_xor(sum, 16, 64);
    sum += __shfl_xor(sum, 32, 64);
    const float rv = 1.f / sum;           // valid for t-row = col
    float rinvT[4];
#pragma unroll
    for (int r = 0; r < 4; ++r)           // epilogue t-row = quad*4+r -> fetch its 1/sum
        rinvT[r] = __shfl(rv, quad * 4 + r, 64);

    vwrite(0);
    __syncthreads();

    // ================= PV via MFMA, 8 chunks of 64 m =================
    floatx4 oacc[4];
#pragma unroll
    for (int dt = 0; dt < 4; ++dt) oacc[dt] = floatx4{0.f, 0.f, 0.f, 0.f};

    const int prow = (w * 16 + col) * 36;
    const int rotR = 8 * (col >> 2);      // un-rotate Vt columns

#pragma unroll
    for (int mc = 0; mc < 8; ++mc) {
        const int p = mc & 1;
        if (mc < 7) vload(mc + 1);

        // P chunk -> LDS (wave-private rows; no barrier needed)
#pragma unroll
        for (int mt = 0; mt < 4; ++mt) {
            const floatx4 pv = accA[mc * 4 + mt];
            uint32_t h0, l0, h1, l1;
            packsplit(pv[0], pv[1], h0, l0);
            packsplit(pv[2], pv[3], h1, l1);
            *(uint2*)(sm + PHIo + prow + mt * 8 + 2 * quad) = make_uint2(h0, h1);
            *(uint2*)(sm + PLOo + prow + mt * 8 + 2 * quad) = make_uint2(l0, l1);
        }

        const uint32_t* VH = sm + p * 4608;
        const uint32_t* VL = VH + 2304;
#pragma unroll
        for (int ks = 0; ks < 2; ++ks) {
            const int po = prow + 16 * ks + 4 * quad;
            Frag pah, pal;
            pah.s = *(const short8*)(sm + PHIo + po);
            pal.s = *(const short8*)(sm + PLOo + po);
            const int cb = ((16 * ks + 4 * quad) + rotR) & 31;
#pragma unroll
            for (int dt = 0; dt < 4; ++dt) {
                const int vo = (dt * 16 + col) * 36 + cb;
                Frag bh, bl;
                bh.s = *(const short8*)(VH + vo);
                bl.s = *(const short8*)(VL + vo);
                oacc[dt] = MFMA(pah.s, bh.s, oacc[dt]);
                oacc[dt] = MFMA(pah.s, bl.s, oacc[dt]);
                oacc[dt] = MFMA(pal.s, bh.s, oacc[dt]);
            }
        }

        if (mc < 7) vwrite(p ^ 1);
        __syncthreads();
    }

    // epilogue: row = t_local (quad*4+r), col = d; apply 1/sum here
    const size_t obase = ((size_t)b * 512 + t0g + w * 16 + quad * 4) * 1024 + h * 64 + col;
#pragma unroll
    for (int dt = 0; dt < 4; ++dt)
#pragma unroll
        for (int r = 0; r < 4; ++r)
            outg[obase + (size_t)r * 1024 + dt * 16] = oacc[dt][r] * rinvT[r];
}

extern "C" void kernel_launch(void* const* d_in, const int* in_sizes, int n_in,
                              void* d_out, int out_size, void* d_ws, size_t ws_size,
                              hipStream_t stream) {
    const float* q   = (const float*)d_in[0];
    const float* k   = (const float*)d_in[1];
    const float* v   = (const float*)d_in[2];
    const float* dtm = (const float*)d_in[3];
    const float* m1w = (const float*)d_in[4];
    const float* m1b = (const float*)d_in[5];
    const float* m2w = (const float*)d_in[6];
    const float* m2b = (const float*)d_in[7];
    float* out = (float*)d_out;

    dim3 grid(4 * 16 * 8);   // 512 workgroups: (b,h) x 8 T-tiles
    dim3 block(256);
    msmha_mfma<<<grid, block, 0, stream>>>(q, k, v, dtm, m1w, m1b, m2w, m2b, out);
}

// Round 2
// 132.431 us; speedup vs baseline: 1.0153x; 1.0153x over previous
//
#include <hip/hip_runtime.h>
#include <stdint.h>

typedef __attribute__((ext_vector_type(8))) short short8;
typedef __attribute__((ext_vector_type(4))) float floatx4;

#define MFMA(a, b, c) __builtin_amdgcn_mfma_f32_16x16x32_bf16(a, b, c, 0, 0, 0)

union Frag { uint32_t u[4]; short8 s; };

// split fp32 x into hi=bf16(trunc), lo=bf16(trunc of exact residual); pack two
// values' bf16 halves into one dword (a -> low16, b -> high16).
__device__ __forceinline__ void packsplit(float a, float b, uint32_t& hi, uint32_t& lo) {
    uint32_t ua = __float_as_uint(a), ub = __float_as_uint(b);
    uint32_t ha = ua & 0xFFFF0000u, hb = ub & 0xFFFF0000u;
    float ra = a - __uint_as_float(ha);   // exact in fp32
    float rb = b - __uint_as_float(hb);
    hi = (ha >> 16) | hb;
    lo = (__float_as_uint(ra) >> 16) | (__float_as_uint(rb) & 0xFFFF0000u);
}

__device__ __forceinline__ float fexp2(float x) {
#if __has_builtin(__builtin_amdgcn_exp2f)
    return __builtin_amdgcn_exp2f(x);     // v_exp_f32 = 2^x
#else
    return exp2f(x);
#endif
}

// LDS dword map, per group g (base gb = g*9216):
//   K hi  gb+0..2304      (64 m-rows x 36 dw)   -> reused as P hi after QK
//   K lo  gb+2304..4608                          -> reused as P lo
//   V hi  gb+4608..6912   (64 d-rows x 36 dw, swizzled cols)
//   V lo  gb+6912..9216
// Epilogue (inside group-1 region): O1 fp32 [64][65] @9216, m1 @13376, l1 @13440.

__global__ __launch_bounds__(512, 4)
void msmha_flash(const float* __restrict__ qg, const float* __restrict__ kg,
                 const float* __restrict__ vg, const float* __restrict__ Dg,
                 const float* __restrict__ m1w, const float* __restrict__ m1b,
                 const float* __restrict__ m2w, const float* __restrict__ m2b,
                 float* __restrict__ outg) {
    __shared__ __align__(16) uint32_t sm[18432];   // 72 KiB
    __shared__ __align__(16) float4 wlds[16];

    const int tid   = threadIdx.x;
    const int w     = tid >> 6;
    const int group = w >> 2;          // 0: m in [0,256), 1: m in [256,512)
    const int gw    = w & 3;           // t-tile within group (16 t-rows)
    const int lane  = tid & 63;
    const int col   = lane & 15;
    const int quad  = lane >> 4;
    const int gtid  = tid & 255;

    const int bid = blockIdx.x;
    const int wgT = bid & 7;           // 8 T-tiles of 64
    const int bh  = bid >> 3;
    const int h   = bh & 15;
    const int b   = bh >> 4;
    const int t0g = wgT * 64;

    const size_t base = (size_t)bh * 512 * 64;
    const float LOG2E = 1.4426950408889634f;

    // Channel weights, pre-scaled (log2e folded; 1/8 dot scale folded into .x)
    if (tid < 16) {
        const float w1d = m1w[h * 32 + tid];
        const float w1s = m1w[h * 32 + 16 + tid];
        const float b1  = m1b[h * 16 + tid];
        const float w2  = m2w[h * 16 + tid];
        wlds[tid] = make_float4(w1d * (0.125f * LOG2E), w1s * LOG2E, b1 * LOG2E, 0.5f * w2);
    }

    // Linear half of relu split: sum_c w2*relu(h) = sum_c (w2/2)h + (w2/2)|h|
    float sA = 0.f, sB = 0.f, sC = 0.f;
#pragma unroll 1
    for (int c = 0; c < 16; ++c) {
        const float w2 = m2w[h * 16 + c];
        sA = fmaf(w2, m1w[h * 32 + c], sA);
        sB = fmaf(w2, m1w[h * 32 + 16 + c], sB);
        sC = fmaf(w2, m1b[h * 16 + c], sC);
    }
    const float Ac = sA * (0.0625f * LOG2E);
    const float Bc = sB * (0.5f * LOG2E);
    const float Cc = fmaf(0.5f, sC, m2b[h]) * LOG2E;

    // Q fragments (B-operand: lane col = t-row, k = quad*8+j), split bf16
    Frag qh[2], ql[2];
    {
        const float* qrow = qg + base + (size_t)(t0g + gw * 16 + col) * 64;
#pragma unroll
        for (int ks = 0; ks < 2; ++ks) {
            const float4 f0 = *(const float4*)(qrow + ks * 32 + quad * 8);
            const float4 f1 = *(const float4*)(qrow + ks * 32 + quad * 8 + 4);
            packsplit(f0.x, f0.y, qh[ks].u[0], ql[ks].u[0]);
            packsplit(f0.z, f0.w, qh[ks].u[1], ql[ks].u[1]);
            packsplit(f1.x, f1.y, qh[ks].u[2], ql[ks].u[2]);
            packsplit(f1.z, f1.w, qh[ks].u[3], ql[ks].u[3]);
        }
    }

    // staging indices (per 256-thread group)
    const int ml0  = gtid >> 4;                 // K rows ml0 + it*16
    const int k4   = gtid & 15;
    const int dgrp = gtid & 15;                 // V d-group (4 d per thread)
    const int m4   = gtid >> 4;                 // V m-group (4 m per thread)
    const int cpV  = (2 * m4 + 8 * ((dgrp >> 1) & 3)) & 31;   // conflict-free swizzle
    const int rsel = col >> 3;

    const int gb = group * 9216;
    uint32_t* KH = sm + gb;
    uint32_t* KL = sm + gb + 2304;
    uint32_t* VH = sm + gb + 4608;
    uint32_t* VL = sm + gb + 6912;

    const int moff = group * 256;
    const float* kc = kg + base + (size_t)moff * 64;
    const float* vc = vg + base + (size_t)moff * 64;
    const float* Dc = Dg + ((size_t)b * 512 + t0g + gw * 16 + col) * 512 + moff + quad * 4;

    float run_m = -3.0e38f, run_l = 0.f;
    floatx4 oacc[4];
#pragma unroll
    for (int dt = 0; dt < 4; ++dt) oacc[dt] = floatx4{0.f, 0.f, 0.f, 0.f};

#pragma unroll 1
    for (int mc = 0; mc < 4; ++mc) {
        const float* kp = kc + (size_t)mc * 64 * 64;
        const float* vp = vc + (size_t)mc * 64 * 64;

        // issue all global loads for this chunk up front
        float4 kr[4], vr[4];
#pragma unroll
        for (int it = 0; it < 4; ++it)
            kr[it] = *(const float4*)(kp + (size_t)(ml0 + it * 16) * 64 + k4 * 4);
#pragma unroll
        for (int i = 0; i < 4; ++i)
            vr[i] = *(const float4*)(vp + (size_t)(4 * m4 + i) * 64 + dgrp * 4);
        float dvf[16];
#pragma unroll
        for (int mt = 0; mt < 4; ++mt) {
            const float4 dd = *(const float4*)(Dc + mc * 64 + mt * 16);
            dvf[mt * 4 + 0] = dd.x; dvf[mt * 4 + 1] = dd.y;
            dvf[mt * 4 + 2] = dd.z; dvf[mt * 4 + 3] = dd.w;
        }

        // pack K -> LDS (bank-uniform: 4 lanes per bank-pair)
#pragma unroll
        for (int it = 0; it < 4; ++it) {
            uint32_t h0, l0, h1, l1;
            packsplit(kr[it].x, kr[it].y, h0, l0);
            packsplit(kr[it].z, kr[it].w, h1, l1);
            const int ml = ml0 + it * 16;
            *(uint2*)(KH + ml * 36 + 2 * k4) = make_uint2(h0, h1);
            *(uint2*)(KL + ml * 36 + 2 * k4) = make_uint2(l0, l1);
        }
        __syncthreads();                       // K staged

        // S^T = K·Q^T via split bf16
        floatx4 sc[4];
#pragma unroll
        for (int mt = 0; mt < 4; ++mt) {
            floatx4 acc = {0.f, 0.f, 0.f, 0.f};
#pragma unroll
            for (int ks = 0; ks < 2; ++ks) {
                const int ro = (mt * 16 + col) * 36 + 16 * ks + 4 * quad;
                Frag ah, al;
                ah.s = *(const short8*)(KH + ro);
                al.s = *(const short8*)(KL + ro);
                acc = MFMA(ah.s, qh[ks].s, acc);
                acc = MFMA(ah.s, ql[ks].s, acc);
                acc = MFMA(al.s, qh[ks].s, acc);
            }
            sc[mt] = acc;   // raw dot
        }

        // fused MLP: mix = Cc + Bc*D + Ac*dot + sum_c (w2/2)|h_c|
        float mix[16];
#pragma unroll
        for (int e = 0; e < 16; ++e) mix[e] = fmaf(dvf[e], Bc, Cc);
#pragma unroll 4
        for (int c = 0; c < 16; ++c) {
            const float4 wv = wlds[c];
#pragma unroll
            for (int mt = 0; mt < 4; ++mt)
#pragma unroll
                for (int r = 0; r < 4; ++r) {
                    const float hh = fmaf(sc[mt][r], wv.x, fmaf(dvf[mt * 4 + r], wv.y, wv.z));
                    mix[mt * 4 + r] = fmaf(fabsf(hh), wv.w, mix[mt * 4 + r]);
                }
        }
#pragma unroll
        for (int mt = 0; mt < 4; ++mt)
#pragma unroll
            for (int r = 0; r < 4; ++r)
                sc[mt][r] = fmaf(sc[mt][r], Ac, mix[mt * 4 + r]);   // log2-domain score

        // pack V -> LDS (loads had QK+MLP time to land); conflict-free swizzle
#pragma unroll
        for (int jj = 0; jj < 4; ++jj) {
            uint32_t h0, l0, h1, l1;
            packsplit(((const float*)&vr[0])[jj], ((const float*)&vr[1])[jj], h0, l0);
            packsplit(((const float*)&vr[2])[jj], ((const float*)&vr[3])[jj], h1, l1);
            const int d = 4 * dgrp + jj;
            *(uint2*)(VH + d * 36 + cpV) = make_uint2(h0, h1);
            *(uint2*)(VL + d * 36 + cpV) = make_uint2(l0, l1);
        }

        // online softmax update (per t=col)
        float cmx = -3.0e38f;
#pragma unroll
        for (int mt = 0; mt < 4; ++mt)
#pragma unroll
            for (int r = 0; r < 4; ++r) cmx = fmaxf(cmx, sc[mt][r]);
        cmx = fmaxf(cmx, __shfl_xor(cmx, 16, 64));
        cmx = fmaxf(cmx, __shfl_xor(cmx, 32, 64));
        const float nm    = fmaxf(run_m, cmx);
        const float scale = fexp2(run_m - nm);
        float csum = 0.f;
#pragma unroll
        for (int mt = 0; mt < 4; ++mt)
#pragma unroll
            for (int r = 0; r < 4; ++r) {
                const float p = fexp2(sc[mt][r] - nm);
                sc[mt][r] = p;
                csum += p;
            }
        csum += __shfl_xor(csum, 16, 64);
        csum += __shfl_xor(csum, 32, 64);
        run_l = fmaf(run_l, scale, csum);
        run_m = nm;
        float sOT[4];
#pragma unroll
        for (int r = 0; r < 4; ++r) sOT[r] = __shfl(scale, quad * 4 + r, 64);
#pragma unroll
        for (int dt = 0; dt < 4; ++dt)
#pragma unroll
            for (int r = 0; r < 4; ++r) oacc[dt][r] *= sOT[r];

        __syncthreads();                       // all QK K-reads done; V visible

        // P -> LDS (reuses K region; wave-private rows, no barrier needed)
        const int prow = (gw * 16 + col) * 36;
#pragma unroll
        for (int mt = 0; mt < 4; ++mt) {
            uint32_t h0, l0, h1, l1;
            packsplit(sc[mt][0], sc[mt][1], h0, l0);
            packsplit(sc[mt][2], sc[mt][3], h1, l1);
            *(uint2*)(KH + prow + mt * 8 + 2 * quad) = make_uint2(h0, h1);
            *(uint2*)(KL + prow + mt * 8 + 2 * quad) = make_uint2(l0, l1);
        }

        // O += P·V
#pragma unroll
        for (int ks = 0; ks < 2; ++ks) {
            const int po = prow + 16 * ks + 4 * quad;
            Frag pah, pal;
            pah.s = *(const short8*)(KH + po);
            pal.s = *(const short8*)(KL + po);
#pragma unroll
            for (int dt = 0; dt < 4; ++dt) {
                const int cbd = ((16 * ks + 4 * quad) + 8 * ((2 * dt + rsel) & 3)) & 31;
                const int vo = (dt * 16 + col) * 36 + cbd;
                Frag bhv, blv;
                bhv.s = *(const short8*)(VH + vo);
                blv.s = *(const short8*)(VL + vo);
                oacc[dt] = MFMA(pah.s, bhv.s, oacc[dt]);
                oacc[dt] = MFMA(pah.s, blv.s, oacc[dt]);
                oacc[dt] = MFMA(pal.s, bhv.s, oacc[dt]);
            }
        }
        __syncthreads();                       // PV reads done before next staging
    }

    // ================= combine the two m-halves, store =================
    float* smf = (float*)sm;
    if (group == 1) {
        if (quad == 0) {
            smf[13376 + gw * 16 + col] = run_m;
            smf[13440 + gw * 16 + col] = run_l;
        }
        const int t = gw * 16 + quad * 4;
#pragma unroll
        for (int dt = 0; dt < 4; ++dt)
#pragma unroll
            for (int r = 0; r < 4; ++r)
                smf[9216 + (t + r) * 65 + dt * 16 + col] = oacc[dt][r];
    }
    __syncthreads();
    if (group == 0) {
        const float m1c = smf[13376 + gw * 16 + col];
        const float l1c = smf[13440 + gw * 16 + col];
        const float M   = fmaxf(run_m, m1c);
        const float s0  = fexp2(run_m - M);
        const float s1  = fexp2(m1c - M);
        const float rdn = 1.f / fmaf(run_l, s0, l1c * s1);
        float s0T[4], s1T[4], rdT[4];
#pragma unroll
        for (int r = 0; r < 4; ++r) {
            s0T[r] = __shfl(s0, quad * 4 + r, 64);
            s1T[r] = __shfl(s1, quad * 4 + r, 64);
            rdT[r] = __shfl(rdn, quad * 4 + r, 64);
        }
        const int t = gw * 16 + quad * 4;
        const size_t obase = ((size_t)b * 512 + t0g + t) * 1024 + h * 64 + col;
#pragma unroll
        for (int dt = 0; dt < 4; ++dt)
#pragma unroll
            for (int r = 0; r < 4; ++r) {
                const float o1 = smf[9216 + (t + r) * 65 + dt * 16 + col];
                outg[obase + (size_t)r * 1024 + dt * 16] =
                    fmaf(oacc[dt][r], s0T[r], o1 * s1T[r]) * rdT[r];
            }
    }
}

extern "C" void kernel_launch(void* const* d_in, const int* in_sizes, int n_in,
                              void* d_out, int out_size, void* d_ws, size_t ws_size,
                              hipStream_t stream) {
    const float* q   = (const float*)d_in[0];
    const float* k   = (const float*)d_in[1];
    const float* v   = (const float*)d_in[2];
    const float* dtm = (const float*)d_in[3];
    const float* m1w = (const float*)d_in[4];
    const float* m1b = (const float*)d_in[5];
    const float* m2w = (const float*)d_in[6];
    const float* m2b = (const float*)d_in[7];
    float* out = (float*)d_out;

    dim3 grid(4 * 16 * 8);   // 512 workgroups: (b,h) x 8 T-tiles
    dim3 block(512);         // 8 waves: 2 m-groups x 4 t-tiles
    msmha_flash<<<grid, block, 0, stream>>>(q, k, v, dtm, m1w, m1b, m2w, m2b, out);
}